// Round 1
// baseline (653.003 us; speedup 1.0000x reference)
//
#include <hip/hip_runtime.h>
#include <math.h>

#define B_ 1024
#define T_ 500
#define K_ 100

// 2-input logsumexp
__device__ __forceinline__ float lse2(float a, float b) {
    float m = fmaxf(a, b);
    return m + __logf(__expf(a - m) + __expf(b - m));
}

// full-wave (64-lane) sum via xor butterfly
__device__ __forceinline__ float wsum(float v) {
#pragma unroll
    for (int m = 32; m > 0; m >>= 1) v += __shfl_xor(v, m, 64);
    return v;
}

__global__ __launch_bounds__(64, 1) void bkt_fwd(
    const int* __restrict__ corr, const int* __restrict__ kc,
    const int* __restrict__ problem, const float* __restrict__ A,
    const float* __restrict__ trans, const float* __restrict__ obs,
    const float* __restrict__ init, float* __restrict__ out)
{
    const int b = blockIdx.x;
    const int lane = threadIdx.x;

    __shared__ int s_kc[T_], s_pr[T_], s_co[T_];
    for (int t = lane; t < T_; t += 64) {
        s_kc[t] = kc[b * T_ + t];
        s_pr[t] = problem[b * T_ + t];
        s_co[t] = corr[b * T_ + t];
    }
    __syncthreads();

    const int k0 = lane;        // KC index 0..63
    const int k1 = lane + 64;   // KC index 64..99 for lanes 0..35
    const bool has1 = (k1 < K_);

    // per-KC log_softmax(trans_logits, axis=1)  (normalize over FIRST state dim, per column o)
    float lt0[2][2], lt1[2][2];
    {
        float4 x = *reinterpret_cast<const float4*>(trans + k0 * 4);
        // x = [s0o0, s0o1, s1o0, s1o1]
        float l0 = lse2(x.x, x.z), l1 = lse2(x.y, x.w);
        lt0[0][0] = x.x - l0; lt0[0][1] = x.y - l1;
        lt0[1][0] = x.z - l0; lt0[1][1] = x.w - l1;
    }
    if (has1) {
        float4 x = *reinterpret_cast<const float4*>(trans + k1 * 4);
        float l0 = lse2(x.x, x.z), l1 = lse2(x.y, x.w);
        lt1[0][0] = x.x - l0; lt1[0][1] = x.y - l1;
        lt1[1][0] = x.z - l0; lt1[1][1] = x.w - l1;
    } else {
        lt1[0][0] = lt1[0][1] = lt1[1][0] = lt1[1][1] = 0.f;
    }

    // alpha init: log_softmax(init_logits, axis=1)
    float al00, al01, al10 = 0.f, al11 = 0.f;
    {
        float2 x = *reinterpret_cast<const float2*>(init + k0 * 2);
        float l = lse2(x.x, x.y);
        al00 = x.x - l; al01 = x.y - l;
    }
    if (has1) {
        float2 x = *reinterpret_cast<const float2*>(init + k1 * 2);
        float l = lse2(x.x, x.y);
        al10 = x.x - l; al11 = x.y - l;
    }

    // software-pipelined prefetch of the A row + obs row
    int row = s_kc[0] * K_;
    float c0 = A[row + k0];
    float c1 = has1 ? A[row + k1] : 0.f;
    float4 ob = *reinterpret_cast<const float4*>(obs + s_pr[0] * 4);

    float* outp = out + (size_t)b * T_ * 2;

    for (int t = 0; t < T_; ++t) {
        const int tn = (t + 1 < T_) ? t + 1 : t;
        const int nrow = s_kc[tn] * K_;
        float nc0 = A[nrow + k0];
        float nc1 = has1 ? A[nrow + k1] : 0.f;
        float4 nob = *reinterpret_cast<const float4*>(obs + s_pr[tn] * 4);

        // 7 weighted reductions over K
        float sc  = wsum(c0 + c1);
        float a20 = wsum(c0 * al00 + c1 * al10);
        float a21 = wsum(c0 * al01 + c1 * al11);
        float q00 = wsum(c0 * lt0[0][0] + c1 * lt1[0][0]);
        float q01 = wsum(c0 * lt0[0][1] + c1 * lt1[0][1]);
        float q10 = wsum(c0 * lt0[1][0] + c1 * lt1[1][0]);
        float q11 = wsum(c0 * lt0[1][1] + c1 * lt1[1][1]);

        // log_obs[s][o] = obs[s][o] - LSE_o (log_softmax over last axis)
        float l0 = lse2(ob.x, ob.y);
        float l1 = lse2(ob.z, ob.w);
        float lo00 = ob.x - l0, lo01 = ob.y - l0;
        float lo10 = ob.z - l1, lo11 = ob.w - l1;

        // predicted output distribution
        float py0 = lse2(lo00 * sc + a20, lo10 * sc + a21);
        float py1 = lse2(lo01 * sc + a20, lo11 * sc + a21);
        float nrm = lse2(py0, py1);
        if (lane == 0) {
            float2 o2 = make_float2(py0 - nrm, py1 - nrm);
            *reinterpret_cast<float2*>(outp + t * 2) = o2;
        }

        // alpha update given observation
        const int y = s_co[t];
        float ol0 = (y == 0 ? lo00 : lo01) * sc;  // obs_ll[s=0]
        float ol1 = (y == 0 ? lo10 : lo11) * sc;  // obs_ll[s=1]
        float u0 = ol0 + a20;   // obs_ll[s2] + a1b[s2], s2=0
        float u1 = ol1 + a21;   // s2=1
        float a30 = lse2(u0 + q00, u1 + q01);
        float a31 = lse2(u0 + q10, u1 + q11);

        al00 = (1.f - c0) * al00 + c0 * a30;
        al01 = (1.f - c0) * al01 + c0 * a31;
        al10 = (1.f - c1) * al10 + c1 * a30;
        al11 = (1.f - c1) * al11 + c1 * a31;

        c0 = nc0; c1 = nc1; ob = nob;
    }
}

extern "C" void kernel_launch(void* const* d_in, const int* in_sizes, int n_in,
                              void* d_out, int out_size, void* d_ws, size_t ws_size,
                              hipStream_t stream) {
    const int*   corr    = (const int*)d_in[0];
    const int*   kc      = (const int*)d_in[1];
    const int*   problem = (const int*)d_in[2];
    const float* A       = (const float*)d_in[3];
    const float* trans   = (const float*)d_in[4];
    const float* obs     = (const float*)d_in[5];
    const float* init    = (const float*)d_in[6];
    float* out = (float*)d_out;

    bkt_fwd<<<B_, 64, 0, stream>>>(corr, kc, problem, A, trans, obs, init, out);
}

// Round 3
// 328.047 us; speedup vs baseline: 1.9906x; 1.9906x over previous
//
#include <hip/hip_runtime.h>
#include <math.h>

#define B_  1024
#define T_  500
#define K_  100
#define NP_ 10000

__device__ __forceinline__ float lse2(float a, float b) {
    float m = fmaxf(a, b);
    return m + __logf(__expf(a - m) + __expf(b - m));
}

template<int CTRL, int RM>
__device__ __forceinline__ float dpp_add(float v) {
    int x = __builtin_amdgcn_update_dpp(0, __float_as_int(v), CTRL, RM, 0xf, true);
    return v + __int_as_float(x);
}

// Full-wave64 sum via DPP (pure VALU, no LDS). Result uniform via readlane(63).
__device__ __forceinline__ float wave_sum(float v) {
    v = dpp_add<0x111, 0xf>(v);   // row_shr:1
    v = dpp_add<0x112, 0xf>(v);   // row_shr:2
    v = dpp_add<0x114, 0xf>(v);   // row_shr:4
    v = dpp_add<0x118, 0xf>(v);   // row_shr:8
    v = dpp_add<0x142, 0xa>(v);   // row_bcast:15 -> rows 1,3
    v = dpp_add<0x143, 0xc>(v);   // row_bcast:31 -> rows 2,3
    return __int_as_float(__builtin_amdgcn_readlane(__float_as_int(v), 63));
}

// ---------------- precompute (indexed by the *kc* stream's values) ----------
// Qtab[p][s][o] = sum_k A[p,k] * log_softmax(trans,axis=1)[k][s][o]
// Stab[p]       = sum_k A[p,k]
// LOtab[p][s][o] = log_softmax(obs[p], over o)   (indexed by *problem* stream)
__global__ __launch_bounds__(64, 4) void bkt_pre(
    const float* __restrict__ A, const float* __restrict__ trans,
    const float* __restrict__ obs, float* __restrict__ Qtab,
    float* __restrict__ Stab, float* __restrict__ LOtab)
{
    const int p = blockIdx.x;
    const int lane = threadIdx.x;
    const int k0 = lane, k1 = lane + 64;
    const bool has1 = (k1 < K_);
    const int k1c = has1 ? k1 : k0;
    const float m1 = has1 ? 1.f : 0.f;

    float4 t0 = *reinterpret_cast<const float4*>(trans + k0 * 4);
    float l00 = lse2(t0.x, t0.z), l01 = lse2(t0.y, t0.w);
    float lt000 = t0.x - l00, lt001 = t0.y - l01;
    float lt010 = t0.z - l00, lt011 = t0.w - l01;
    float4 t1 = *reinterpret_cast<const float4*>(trans + k1c * 4);
    float l10 = lse2(t1.x, t1.z), l11 = lse2(t1.y, t1.w);
    float lt100 = t1.x - l10, lt101 = t1.y - l11;
    float lt110 = t1.z - l10, lt111 = t1.w - l11;

    const float* ar = A + (size_t)p * K_;
    float c0 = ar[k0];
    float c1 = ar[k1c] * m1;

    float sc  = wave_sum(c0 + c1);
    float q00 = wave_sum(c0 * lt000 + c1 * lt100);
    float q01 = wave_sum(c0 * lt001 + c1 * lt101);
    float q10 = wave_sum(c0 * lt010 + c1 * lt110);
    float q11 = wave_sum(c0 * lt011 + c1 * lt111);

    float4 ob = *reinterpret_cast<const float4*>(obs + (size_t)p * 4);
    float l0 = lse2(ob.x, ob.y), l1 = lse2(ob.z, ob.w);

    if (lane == 0) {
        reinterpret_cast<float4*>(Qtab)[p] = make_float4(q00, q01, q10, q11);
        Stab[p] = sc;
        reinterpret_cast<float4*>(LOtab)[p] =
            make_float4(ob.x - l0, ob.y - l0, ob.z - l1, ob.w - l1);
    }
}

// ---------------- main sequential scan ----------------
struct Raw { float c0, c1, S; float4 Q, L; int y; };
struct Der { float c0, c1, g00, g01, g10, g11, h00, h01, h10, h11; };

__global__ __launch_bounds__(64, 1) void bkt_main(
    const int* __restrict__ corr, const int* __restrict__ kc,
    const int* __restrict__ problem, const float* __restrict__ A,
    const float* __restrict__ init, const float* __restrict__ Qtab,
    const float* __restrict__ Stab, const float* __restrict__ LOtab,
    float* __restrict__ out)
{
    const int b = blockIdx.x;
    const int lane = threadIdx.x;
    const int k0 = lane, k1 = lane + 64;
    const bool has1 = (k1 < K_);
    const int k1c = has1 ? k1 : k0;
    const float m1 = has1 ? 1.f : 0.f;

    const int* kcb = kc + (size_t)b * T_;
    const int* prb = problem + (size_t)b * T_;
    const int* cob = corr + (size_t)b * T_;
    float* outp = out + (size_t)b * T_ * 2;

    // alpha init: log_softmax(init_logits, axis=1); invalid k1 lanes -> 0 (never used: c1=0)
    float al00, al01, al10 = 0.f, al11 = 0.f;
    {
        float2 x = *reinterpret_cast<const float2*>(init + k0 * 2);
        float l = lse2(x.x, x.y);
        al00 = x.x - l; al01 = x.y - l;
    }
    {
        float2 x = *reinterpret_cast<const float2*>(init + k1c * 2);
        float l = lse2(x.x, x.y);
        al10 = (x.x - l) * m1; al11 = (x.y - l) * m1;
    }

    // Q and S are functions of the kc stream; L of the problem stream.
#define ISSUE(raw, kcv, prv, yv) {                                        \
        const float* ar_ = A + (size_t)(kcv) * K_;                        \
        raw.c0 = ar_[k0];                                                 \
        raw.c1 = ar_[k1c] * m1;                                           \
        raw.Q = reinterpret_cast<const float4*>(Qtab)[(size_t)(kcv)];     \
        raw.S = Stab[(size_t)(kcv)];                                      \
        raw.L = reinterpret_cast<const float4*>(LOtab)[(size_t)(prv)];    \
        raw.y = (yv); }

#define DERIVE(d, raw) {                                                  \
        d.h00 = raw.L.x * raw.S; d.h01 = raw.L.y * raw.S;                 \
        d.h10 = raw.L.z * raw.S; d.h11 = raw.L.w * raw.S;                 \
        float ol0 = (raw.y == 0) ? d.h00 : d.h01;                         \
        float ol1 = (raw.y == 0) ? d.h10 : d.h11;                         \
        d.g00 = ol0 + raw.Q.x; d.g01 = ol1 + raw.Q.y;                     \
        d.g10 = ol0 + raw.Q.z; d.g11 = ol1 + raw.Q.w;                     \
        d.c0 = raw.c0; d.c1 = raw.c1; }

#define STEP(t, d) {                                                      \
        float p0 = d.c0 * al00 + d.c1 * al10;                             \
        float p1 = d.c0 * al01 + d.c1 * al11;                             \
        float a20 = wave_sum(p0);                                         \
        float a21 = wave_sum(p1);                                         \
        float a30 = lse2(d.g00 + a20, d.g01 + a21);                       \
        float a31 = lse2(d.g10 + a20, d.g11 + a21);                       \
        al00 += d.c0 * (a30 - al00);                                      \
        al01 += d.c0 * (a31 - al01);                                      \
        al10 += d.c1 * (a30 - al10);                                      \
        al11 += d.c1 * (a31 - al11);                                      \
        float py0 = lse2(d.h00 + a20, d.h10 + a21);                       \
        float py1 = lse2(d.h01 + a20, d.h11 + a21);                       \
        float nrm = lse2(py0, py1);                                       \
        if (lane == 0) {                                                  \
            *reinterpret_cast<float2*>(outp + (size_t)(t) * 2) =          \
                make_float2(py0 - nrm, py1 - nrm);                        \
        } }

    Raw rA, rB; Der dA, dB;

    // prologue: idx(0),(1) -> data(0),(1) -> derived(0),(1); idx slots advance to (2),(3)
    int kA = kcb[0], pA = prb[0], yA = cob[0];
    int kB = kcb[1], pB = prb[1], yB = cob[1];
    ISSUE(rA, kA, pA, yA);
    ISSUE(rB, kB, pB, yB);
    kA = kcb[2]; pA = prb[2]; yA = cob[2];
    kB = kcb[3]; pB = prb[3]; yB = cob[3];
    DERIVE(dA, rA);
    DERIVE(dB, rB);

    for (int t = 0; t < T_; t += 2) {
        // issue data for t+2, t+3 using prefetched indices
        ISSUE(rA, kA, pA, yA);
        ISSUE(rB, kB, pB, yB);
        // prefetch indices for t+4, t+5 (clamped)
        int t4 = t + 4 < T_ ? t + 4 : T_ - 1;
        int t5 = t + 5 < T_ ? t + 5 : T_ - 1;
        kA = kcb[t4]; pA = prb[t4]; yA = cob[t4];
        kB = kcb[t5]; pB = prb[t5]; yB = cob[t5];
        // the sequential chain
        STEP(t, dA);
        STEP(t + 1, dB);
        // consume raws (vmcnt waits land here, ~2 steps after issue)
        DERIVE(dA, rA);
        DERIVE(dB, rB);
    }
#undef ISSUE
#undef DERIVE
#undef STEP
}

extern "C" void kernel_launch(void* const* d_in, const int* in_sizes, int n_in,
                              void* d_out, int out_size, void* d_ws, size_t ws_size,
                              hipStream_t stream) {
    const int*   corr    = (const int*)d_in[0];
    const int*   kc      = (const int*)d_in[1];
    const int*   problem = (const int*)d_in[2];
    const float* A       = (const float*)d_in[3];
    const float* trans   = (const float*)d_in[4];
    const float* obs     = (const float*)d_in[5];
    const float* init    = (const float*)d_in[6];
    float* out = (float*)d_out;

    // workspace layout: Qtab (NP*4 f32) | LOtab (NP*4 f32) | Stab (NP f32)
    float* Qtab  = (float*)d_ws;
    float* LOtab = Qtab + (size_t)NP_ * 4;
    float* Stab  = LOtab + (size_t)NP_ * 4;

    bkt_pre<<<NP_, 64, 0, stream>>>(A, trans, obs, Qtab, Stab, LOtab);
    bkt_main<<<B_, 64, 0, stream>>>(corr, kc, problem, A, init, Qtab, Stab, LOtab, out);
}